// Round 5
// baseline (406.124 us; speedup 1.0000x reference)
//
#include <hip/hip_runtime.h>
#include <math.h>

#define C_ 512
#define D_ 256
#define KS_ 4
#define TOPK_ 10
#define NEG 1e20f

// chunk permutation: XOR bit0 with bit3 (involution). A wave's 64 b128 reads
// (chunks 2l, 2l+1) cover all 32 banks with only 2-way aliasing (free, m136).
__device__ __forceinline__ int csw2(int g) { return g ^ ((g >> 3) & 1); }

#define BSTR 516   // ==4 mod 32 -> transposed scalar writes 2-way max; *4B % 16 == 0
#define ASTR 36
#define BBUF (16 * BSTR)
#define ABUF (16 * ASTR)

// NOTE: __launch_bounds__(256,w) empirically caps VGPR at 256/w (R1-R4). w=2 -> 128.
extern "C" __global__ __launch_bounds__(256, 2)
void graph_learner(const float* __restrict__ ctx,
                   const int* __restrict__ cmask,
                   const float* __restrict__ W,
                   const float* __restrict__ mu_g,
                   const float* __restrict__ pr_g,
                   float* __restrict__ out)
{
    __shared__ __align__(16) float wbar_s[D_];
    __shared__ __align__(16) float a_s[2 * ABUF];   // double-buffered A k-slice (transposed)
    __shared__ __align__(16) float b_s[2 * BBUF];   // double-buffered B k-slice (transposed+swizzled)
    __shared__ unsigned int vmask_s[16];

    const int tid  = threadIdx.x;
    const int lane = tid & 63;
    const int wv   = tid >> 6;
    const int w8   = wv * 8;

    // XCD swizzle: the 16 row-blocks sharing one ctx[b,t] panel land on one XCD's L2
    const int blk = blockIdx.x;
    const int bt  = (blk & 7) * 4 + ((blk >> 3) & 3);   // 0..31
    const int c0  = (blk >> 5) * 32;                    // row tile 0..480
    const int b   = bt >> 3;

    const float* ctx_bt = ctx + (size_t)bt * (C_ * D_);
    const int*   mask_b = cmask + b * C_;

    // wbar = mean_p relu(W[p,:])
    {
        float w0 = W[tid], w1 = W[D_ + tid], w2 = W[2 * D_ + tid], w3 = W[3 * D_ + tid];
        wbar_s[tid] = 0.25f * (fmaxf(w0, 0.f) + fmaxf(w1, 0.f) + fmaxf(w2, 0.f) + fmaxf(w3, 0.f));
    }
    if (tid < 16) {
        unsigned int m = 0;
        for (int i = 0; i < 32; ++i)
            m |= (mask_b[tid * 32 + i] > 0 ? 1u : 0u) << i;
        vmask_s[tid] = m;
    }

    // ---- hoisted staging geometry ----
    const int brow = tid >> 2;
    const int bq   = tid & 3;
    const float* bsrc = ctx_bt + (size_t)brow * D_ + bq * 4;
    const int bwbase = (4 * bq) * BSTR + 4 * csw2(brow >> 2) + (brow & 3);
    const int ar_ = tid >> 2;        // valid when tid<128
    const int aq  = tid & 3;
    const float* asrc = ctx_bt + (size_t)(c0 + ar_) * D_ + aq * 4;
    const int awbase = (4 * aq) * ASTR + ar_;
    const int bc0 = 4 * csw2(2 * lane);
    const int bc1 = 4 * csw2(2 * lane + 1);

    __syncthreads();   // wbar_s / vmask_s ready

    // prologue: stage k-slice 0 into buffer 0 (latency exposed once)
    #pragma unroll
    for (int i = 0; i < 8; ++i) {
        float4 v = *(const float4*)(bsrc + (size_t)i * 64 * D_);
        b_s[bwbase + 0 * BSTR + i * 64] = v.x;
        b_s[bwbase + 1 * BSTR + i * 64] = v.y;
        b_s[bwbase + 2 * BSTR + i * 64] = v.z;
        b_s[bwbase + 3 * BSTR + i * 64] = v.w;
    }
    if (tid < 128) {
        float4 v  = *(const float4*)asrc;
        float4 wb = *(const float4*)(wbar_s + aq * 4);
        a_s[awbase + 0 * ASTR] = v.x * wb.x;
        a_s[awbase + 1 * ASTR] = v.y * wb.y;
        a_s[awbase + 2 * ASTR] = v.z * wb.z;
        a_s[awbase + 3 * ASTR] = v.w * wb.w;
    }

    float acc[8][8];
    #pragma unroll
    for (int j = 0; j < 8; ++j)
        #pragma unroll
        for (int i = 0; i < 8; ++i) acc[j][i] = 0.f;

    // 4 consecutive kk of the inner product (order identical to R4 -> bit-identical)
    #define FMA4(K0)                                                          \
        _Pragma("unroll")                                                     \
        for (int kk = (K0); kk < (K0) + 4; ++kk) {                            \
            float4 av0 = *(const float4*)(acur + kk * ASTR + w8);             \
            float4 av1 = *(const float4*)(acur + kk * ASTR + w8 + 4);         \
            float4 bv0 = *(const float4*)(bcur + kk * BSTR + bc0);            \
            float4 bv1 = *(const float4*)(bcur + kk * BSTR + bc1);            \
            float ar8[8] = {av0.x, av0.y, av0.z, av0.w, av1.x, av1.y, av1.z, av1.w}; \
            float br8[8] = {bv0.x, bv0.y, bv0.z, bv0.w, bv1.x, bv1.y, bv1.z, bv1.w}; \
            _Pragma("unroll")                                                 \
            for (int j = 0; j < 8; ++j)                                       \
                _Pragma("unroll")                                             \
                for (int i = 0; i < 8; ++i)                                   \
                    acc[j][i] += ar8[j] * br8[i];                             \
        }

    #define BWRITE(L, I)                                                     \
        bnxt[bwbase + 0 * BSTR + (I) * 64] = (L).x;                           \
        bnxt[bwbase + 1 * BSTR + (I) * 64] = (L).y;                           \
        bnxt[bwbase + 2 * BSTR + (I) * 64] = (L).z;                           \
        bnxt[bwbase + 3 * BSTR + (I) * 64] = (L).w;

    for (int kt = 0; kt < 16; ++kt) {
        const float* bcur = b_s + (kt & 1) * BBUF;
        const float* acur = a_s + (kt & 1) * ABUF;
        float* bnxt = b_s + ((kt & 1) ^ 1) * BBUF;
        float* anxt = a_s + ((kt & 1) ^ 1) * ABUF;
        const float* nsrc = bsrc + (kt + 1) * 16;
        const bool pf = (kt < 15);
        // single barrier per kt: everyone done reading buf[cur^1] (written kt-1)
        __syncthreads();

        float4 L0, L1, A0;
        if (pf) {
            L0 = *(const float4*)(nsrc + (size_t)0 * 64 * D_);
            L1 = *(const float4*)(nsrc + (size_t)1 * 64 * D_);
            if (tid < 128) A0 = *(const float4*)(asrc + (kt + 1) * 16);
        }
        FMA4(0)
        float4 L2, L3;
        if (pf) {
            BWRITE(L0, 0) BWRITE(L1, 1)
            L2 = *(const float4*)(nsrc + (size_t)2 * 64 * D_);
            L3 = *(const float4*)(nsrc + (size_t)3 * 64 * D_);
        }
        FMA4(4)
        float4 L4, L5;
        if (pf) {
            BWRITE(L2, 2) BWRITE(L3, 3)
            L4 = *(const float4*)(nsrc + (size_t)4 * 64 * D_);
            L5 = *(const float4*)(nsrc + (size_t)5 * 64 * D_);
        }
        FMA4(8)
        float4 L6, L7;
        if (pf) {
            BWRITE(L4, 4) BWRITE(L5, 5)
            L6 = *(const float4*)(nsrc + (size_t)6 * 64 * D_);
            L7 = *(const float4*)(nsrc + (size_t)7 * 64 * D_);
        }
        FMA4(12)
        if (pf) {
            BWRITE(L6, 6) BWRITE(L7, 7)
            if (tid < 128) {
                float4 wb = *(const float4*)(wbar_s + (kt + 1) * 16 + aq * 4);
                anxt[awbase + 0 * ASTR] = A0.x * wb.x;
                anxt[awbase + 1 * ASTR] = A0.y * wb.y;
                anxt[awbase + 2 * ASTR] = A0.z * wb.z;
                anxt[awbase + 3 * ASTR] = A0.w * wb.w;
            }
        }
    }
    #undef FMA4
    #undef BWRITE

    // zero this block's output region NOW (fire-and-forget); the drain overlaps
    // the long top-k/softmax compute below and is collected by the pre-scatter barrier.
    {
        const float4 z = make_float4(0.f, 0.f, 0.f, 0.f);
        #pragma unroll
        for (int ks = 0; ks < KS_; ++ks) {
            float* ob = out + ((size_t)(bt * KS_ + ks) * C_ + c0) * C_;
            #pragma unroll
            for (int i = 0; i < 16; ++i)
                *(float4*)(ob + (size_t)(tid + i * 256) * 4) = z;
        }
    }

    // ---- epilogue: mask, top-10, softmax, spatial (compute phase) ----
    const unsigned int em8 = (vmask_s[lane >> 2] >> ((lane & 3) * 8)) & 0xffu;
    const float mu0 = mu_g[0], mu1 = mu_g[1], mu2 = mu_g[2], mu3 = mu_g[3];
    const float pr0 = pr_g[0], pr1 = pr_g[1], pr2 = pr_g[2], pr3 = pr_g[3];

    float oval[8];
    int   ooff[8];

    #pragma unroll
    for (int jr = 0; jr < 8; ++jr) {
        const int c  = c0 + w8 + jr;
        const int vr = mask_b[c];
        float row[8];
        #pragma unroll
        for (int i = 0; i < 8; ++i) {
            bool ok = (vr > 0) && ((em8 >> i) & 1u);
            row[i] = ok ? acc[jr][i] : -NEG;
        }
        float tv[TOPK_];
        int   te[TOPK_];
        unsigned int taken = 0;
        #pragma unroll
        for (int j = 0; j < TOPK_; ++j) {
            float lv = -3.3e38f;
            int   li = 0;
            #pragma unroll
            for (int i = 0; i < 8; ++i) {
                bool better = (!((taken >> i) & 1u)) && (row[i] > lv);
                lv = better ? row[i] : lv;
                li = better ? i : li;
            }
            int le = lane * 8 + li;
            #pragma unroll
            for (int off = 1; off < 64; off <<= 1) {
                float ov = __shfl_xor(lv, off);
                int   oe = __shfl_xor(le, off);
                bool take = (ov > lv) || (ov == lv && oe < le);
                lv = take ? ov : lv;
                le = take ? oe : le;
            }
            tv[j] = lv;
            te[j] = le;
            if ((le >> 3) == lane) taken |= 1u << (le & 7);
        }
        const float mx = tv[0];
        float ssum = 0.f;
        #pragma unroll
        for (int j = 0; j < TOPK_; ++j) ssum += expf(tv[j] - mx);

        // per-lane (ks,j) pair; lanes >=40 compute garbage but never store
        {
            const int ksq = lane / 10;
            const int myj = lane - ksq * 10;
            const float mu = (ksq == 0) ? mu0 : (ksq == 1) ? mu1 : (ksq == 2) ? mu2 : mu3;
            const float pr = (ksq == 0) ? pr0 : (ksq == 1) ? pr1 : (ksq == 2) ? pr2 : pr3;
            float sps = 0.f, spj = 0.f, tvj = 0.f;
            int ej = 0;
            #pragma unroll
            for (int j = 0; j < TOPK_; ++j) {
                float d = fabsf((float)(te[j] - c));
                d = fminf(d, 160.f) * (1.0f / 160.0f);
                float x  = d - mu;
                float sp = expf(-0.5f * x * x * pr * pr);
                sps += sp;
                if (j == myj) { spj = sp; tvj = tv[j]; ej = te[j]; }
            }
            const int ksq4 = (ksq < 3) ? ksq : 3;   // keep offset in-bounds for lanes>=40
            oval[jr] = (expf(tvj - mx) / ssum) * (spj / sps);
            ooff[jr] = ((bt * KS_ + ksq4) * C_ + c) * C_ + ej;
        }
    }

    // drain zero-stores (covered by the compute above), then scatter
    __syncthreads();
    if (lane < 40) {
        #pragma unroll
        for (int jr = 0; jr < 8; ++jr)
            out[ooff[jr]] = oval[jr];
    }
}

extern "C" void kernel_launch(void* const* d_in, const int* in_sizes, int n_in,
                              void* d_out, int out_size, void* d_ws, size_t ws_size,
                              hipStream_t stream) {
    (void)in_sizes; (void)n_in; (void)d_ws; (void)ws_size; (void)out_size;
    const float* ctx   = (const float*)d_in[0];
    const int*   cmask = (const int*)d_in[1];
    const float* W     = (const float*)d_in[2];
    const float* mu    = (const float*)d_in[3];
    const float* pr    = (const float*)d_in[4];
    graph_learner<<<dim3(512), dim3(256), 0, stream>>>(ctx, cmask, W, mu, pr, (float*)d_out);
}

// Round 6
// 134.727 us; speedup vs baseline: 3.0144x; 3.0144x over previous
//
#include <hip/hip_runtime.h>
#include <math.h>

#define C_ 512
#define D_ 256
#define KS_ 4
#define TOPK_ 10
#define NEG 1e20f

typedef float v2f __attribute__((ext_vector_type(2)));

// chunk permutation: XOR bit0 with bit3 (involution). A wave's 64 b128 reads
// (chunks 2l, 2l+1) cover all 32 banks with only 2-way aliasing (free, m136).
__device__ __forceinline__ int csw2(int g) { return g ^ ((g >> 3) & 1); }

#define BSTR 516   // ==4 mod 32 -> transposed scalar writes conflict-free; *4B % 16 == 0
#define ASTR 36

// NOTE: __launch_bounds__(256,w) empirically caps VGPR at 256/w (R1-R5). w=2 -> 128.
// R4 (96 VGPR, zero spill) is the proven register envelope — no reg prefetch, no
// epilogue arrays. R5's spill (1GB scratch) came from exceeding it.
extern "C" __global__ __launch_bounds__(256, 2)
void graph_learner(const float* __restrict__ ctx,
                   const int* __restrict__ cmask,
                   const float* __restrict__ W,
                   const float* __restrict__ mu_g,
                   const float* __restrict__ pr_g,
                   float* __restrict__ out)
{
    __shared__ __align__(16) float wbar_s[D_];
    __shared__ __align__(16) float a_s[16 * ASTR];   // A k-slice transposed: a_s[kk*ASTR + r]
    __shared__ __align__(16) float b_s[16 * BSTR];   // B k-slice transposed+swizzled
    __shared__ __align__(8)  float res_s[2560];      // 4 waves x 8 jr x 40 x {val, off-bits}
    __shared__ unsigned int vmask_s[16];

    const int tid  = threadIdx.x;
    const int lane = tid & 63;
    const int wv   = tid >> 6;
    const int w8   = wv * 8;

    // XCD swizzle: the 16 row-blocks sharing one ctx[b,t] panel land on one XCD's L2
    const int blk = blockIdx.x;
    const int bt  = (blk & 7) * 4 + ((blk >> 3) & 3);   // 0..31
    const int c0  = (blk >> 5) * 32;                    // row tile 0..480
    const int b   = bt >> 3;

    const float* ctx_bt = ctx + (size_t)bt * (C_ * D_);
    const int*   mask_b = cmask + b * C_;

    // wbar = mean_p relu(W[p,:])
    {
        float w0 = W[tid], w1 = W[D_ + tid], w2 = W[2 * D_ + tid], w3 = W[3 * D_ + tid];
        wbar_s[tid] = 0.25f * (fmaxf(w0, 0.f) + fmaxf(w1, 0.f) + fmaxf(w2, 0.f) + fmaxf(w3, 0.f));
    }
    if (tid < 16) {
        unsigned int m = 0;
        for (int i = 0; i < 32; ++i)
            m |= (mask_b[tid * 32 + i] > 0 ? 1u : 0u) << i;
        vmask_s[tid] = m;
    }

    // ---- hoisted staging geometry (R4, unchanged) ----
    const int brow = tid >> 2;
    const int bq   = tid & 3;
    const float* bsrc = ctx_bt + (size_t)brow * D_ + bq * 4;
    const int bwbase = (4 * bq) * BSTR + 4 * csw2(brow >> 2) + (brow & 3);
    const int ar_ = tid >> 2;        // valid when tid<128
    const int aq  = tid & 3;
    const float* asrc = ctx_bt + (size_t)(c0 + ar_) * D_ + aq * 4;
    const int awbase = (4 * aq) * ASTR + ar_;
    const int bc0 = 4 * csw2(2 * lane);
    const int bc1 = 4 * csw2(2 * lane + 1);

    v2f acc2[8][4];                  // acc2[j][t] = {acc[j][2t], acc[j][2t+1]}
    #pragma unroll
    for (int j = 0; j < 8; ++j)
        #pragma unroll
        for (int t = 0; t < 4; ++t) acc2[j][t] = (v2f){0.f, 0.f};

    for (int kt = 0; kt < 16; ++kt) {
        __syncthreads();             // previous slice consumed (and wbar/vmask ready at kt=0)
        // register-frugal staging: load -> immediate LDS write (R4 shape, 96 VGPR proven)
        #pragma unroll
        for (int i = 0; i < 8; ++i) {
            float4 v = *(const float4*)(bsrc + (size_t)i * 64 * D_ + kt * 16);
            b_s[bwbase + 0 * BSTR + i * 64] = v.x;
            b_s[bwbase + 1 * BSTR + i * 64] = v.y;
            b_s[bwbase + 2 * BSTR + i * 64] = v.z;
            b_s[bwbase + 3 * BSTR + i * 64] = v.w;
        }
        if (tid < 128) {
            float4 v  = *(const float4*)(asrc + kt * 16);
            float4 wb = *(const float4*)(wbar_s + kt * 16 + aq * 4);
            a_s[awbase + 0 * ASTR] = v.x * wb.x;
            a_s[awbase + 1 * ASTR] = v.y * wb.y;
            a_s[awbase + 2 * ASTR] = v.z * wb.z;
            a_s[awbase + 3 * ASTR] = v.w * wb.w;
        }
        __syncthreads();
        #pragma unroll
        for (int kk = 0; kk < 16; ++kk) {
            float4 av0 = *(const float4*)(a_s + kk * ASTR + w8);       // wave-uniform broadcast
            float4 av1 = *(const float4*)(a_s + kk * ASTR + w8 + 4);
            float4 bv0 = *(const float4*)(b_s + kk * BSTR + bc0);
            float4 bv1 = *(const float4*)(b_s + kk * BSTR + bc1);
            v2f b20 = (v2f){bv0.x, bv0.y};   // natural register pairs from the b128 load
            v2f b21 = (v2f){bv0.z, bv0.w};
            v2f b22 = (v2f){bv1.x, bv1.y};
            v2f b23 = (v2f){bv1.z, bv1.w};
            float ar8[8] = {av0.x, av0.y, av0.z, av0.w, av1.x, av1.y, av1.z, av1.w};
            #pragma unroll
            for (int j = 0; j < 8; ++j) {
                v2f a2 = (v2f){ar8[j], ar8[j]};
                // per-element accumulation order identical to scalar (each 32-bit
                // half is an independent IEEE fp32 FMA chain over kk) -> bit-exact
                asm("v_pk_fma_f32 %0, %1, %2, %0" : "+v"(acc2[j][0]) : "v"(a2), "v"(b20));
                asm("v_pk_fma_f32 %0, %1, %2, %0" : "+v"(acc2[j][1]) : "v"(a2), "v"(b21));
                asm("v_pk_fma_f32 %0, %1, %2, %0" : "+v"(acc2[j][2]) : "v"(a2), "v"(b22));
                asm("v_pk_fma_f32 %0, %1, %2, %0" : "+v"(acc2[j][3]) : "v"(a2), "v"(b23));
            }
        }
    }

    // zero this block's output region NOW (fire-and-forget). The vmcnt(0) drain
    // happens at the pre-scatter __syncthreads below, covered by the top-k compute.
    {
        const float4 z = make_float4(0.f, 0.f, 0.f, 0.f);
        #pragma unroll
        for (int ks = 0; ks < KS_; ++ks) {
            float* ob = out + ((size_t)(bt * KS_ + ks) * C_ + c0) * C_;
            #pragma unroll
            for (int i = 0; i < 16; ++i)
                *(float4*)(ob + (size_t)(tid + i * 256) * 4) = z;
        }
    }

    // ---- epilogue: mask, top-10, softmax, spatial -> LDS result table ----
    const unsigned int em8 = (vmask_s[lane >> 2] >> ((lane & 3) * 8)) & 0xffu;
    const float mu0 = mu_g[0], mu1 = mu_g[1], mu2 = mu_g[2], mu3 = mu_g[3];
    const float pr0 = pr_g[0], pr1 = pr_g[1], pr2 = pr_g[2], pr3 = pr_g[3];

    #pragma unroll
    for (int jr = 0; jr < 8; ++jr) {
        const int c  = c0 + w8 + jr;
        const int vr = mask_b[c];
        float row[8];
        #pragma unroll
        for (int t = 0; t < 4; ++t) { row[2 * t] = acc2[jr][t].x; row[2 * t + 1] = acc2[jr][t].y; }
        #pragma unroll
        for (int i = 0; i < 8; ++i) {
            bool ok = (vr > 0) && ((em8 >> i) & 1u);
            row[i] = ok ? row[i] : -NEG;
        }
        float tv[TOPK_];
        int   te[TOPK_];
        unsigned int taken = 0;
        #pragma unroll
        for (int j = 0; j < TOPK_; ++j) {
            float lv = -3.3e38f;
            int   li = 0;
            #pragma unroll
            for (int i = 0; i < 8; ++i) {
                bool better = (!((taken >> i) & 1u)) && (row[i] > lv);
                lv = better ? row[i] : lv;
                li = better ? i : li;
            }
            int le = lane * 8 + li;
            #pragma unroll
            for (int off = 1; off < 64; off <<= 1) {
                float ov = __shfl_xor(lv, off);
                int   oe = __shfl_xor(le, off);
                bool take = (ov > lv) || (ov == lv && oe < le);
                lv = take ? ov : lv;
                le = take ? oe : le;
            }
            tv[j] = lv;
            te[j] = le;
            if ((le >> 3) == lane) taken |= 1u << (le & 7);
        }
        const float mx = tv[0];
        float ssum = 0.f;
        #pragma unroll
        for (int j = 0; j < TOPK_; ++j) ssum += expf(tv[j] - mx);

        if (lane < 40) {
            const int ksq = lane / 10;
            const int myj = lane - ksq * 10;
            const float mu = (ksq == 0) ? mu0 : (ksq == 1) ? mu1 : (ksq == 2) ? mu2 : mu3;
            const float pr = (ksq == 0) ? pr0 : (ksq == 1) ? pr1 : (ksq == 2) ? pr2 : pr3;
            float sps = 0.f, spj = 0.f, tvj = 0.f;
            int ej = 0;
            #pragma unroll
            for (int j = 0; j < TOPK_; ++j) {
                float d = fabsf((float)(te[j] - c));
                d = fminf(d, 160.f) * (1.0f / 160.0f);
                float x  = d - mu;
                float sp = expf(-0.5f * x * x * pr * pr);
                sps += sp;
                if (j == myj) { spj = sp; tvj = tv[j]; ej = te[j]; }
            }
            float val = (expf(tvj - mx) / ssum) * (spj / sps);
            int   off = ((bt * KS_ + ksq) * C_ + c) * C_ + ej;
            int   slot = (((wv * 8 + jr) * 40) + lane) * 2;
            res_s[slot]     = val;
            res_s[slot + 1] = __int_as_float(off);
        }
    }

    // drain zero-stores (overlapped by the compute above) + res_s visibility
    __syncthreads();
    // compact scatter: 1280 pairs, 5 per thread
    #pragma unroll
    for (int i = 0; i < 5; ++i) {
        int p = tid * 5 + i;
        float v   = res_s[2 * p];
        int   off = __float_as_int(res_s[2 * p + 1]);
        out[off] = v;
    }
}

extern "C" void kernel_launch(void* const* d_in, const int* in_sizes, int n_in,
                              void* d_out, int out_size, void* d_ws, size_t ws_size,
                              hipStream_t stream) {
    (void)in_sizes; (void)n_in; (void)d_ws; (void)ws_size; (void)out_size;
    const float* ctx   = (const float*)d_in[0];
    const int*   cmask = (const int*)d_in[1];
    const float* W     = (const float*)d_in[2];
    const float* mu    = (const float*)d_in[3];
    const float* pr    = (const float*)d_in[4];
    graph_learner<<<dim3(512), dim3(256), 0, stream>>>(ctx, cmask, W, mu, pr, (float*)d_out);
}

// Round 7
// 110.235 us; speedup vs baseline: 3.6842x; 1.2222x over previous
//
#include <hip/hip_runtime.h>
#include <math.h>

#define C_ 512
#define D_ 256
#define KS_ 4
#define TOPK_ 10
#define NEG 1e20f

typedef float v2f __attribute__((ext_vector_type(2)));

__device__ __forceinline__ int csw2(int g) { return g ^ ((g >> 3) & 1); }

#define ASTR 36     // a_s row stride: %4==0 -> b128-aligned broadcast reads
#define BSTR1 130   // k1 b_s row stride: even -> b64 aligned; contiguous reads are conflict-free

// ============================ Kernel 1: GEMM =============================
// attention[bt][r][e] -> ws. Tile 32 rows x 128 cols, grid 2048 (8 blocks/CU),
// per-thread 8x2 acc. kk-sequential fp32 FMA -> bit-identical to fused path.
extern "C" __global__ __launch_bounds__(256, 4)
void gemm_attn(const float* __restrict__ ctx,
               const float* __restrict__ W,
               float* __restrict__ ws)
{
    __shared__ __align__(16) float wbar_s[D_];
    __shared__ __align__(16) float a_s[16 * ASTR];    // A k-slice transposed (32 rows)
    __shared__ __align__(16) float b_s[16 * BSTR1];   // B k-slice transposed (128 cols)

    const int tid  = threadIdx.x;
    const int lane = tid & 63;
    const int wv   = tid >> 6;
    const int w8   = wv * 8;

    // XCD swizzle: all 64 tiles of one ctx[b,t] panel land on one XCD's L2
    const int blk  = blockIdx.x;
    const int bt   = (blk & 7) * 4 + ((blk >> 3) & 3);   // 0..31
    const int tile = blk >> 5;                           // 0..63
    const int c0   = (tile & 15) * 32;                   // row tile
    const int n0   = (tile >> 4) * 128;                  // col tile

    const float* ctx_bt = ctx + (size_t)bt * (C_ * D_);

    // wbar = mean_p relu(W[p,:])
    {
        float w0 = W[tid], w1 = W[D_ + tid], w2 = W[2 * D_ + tid], w3 = W[3 * D_ + tid];
        wbar_s[tid] = 0.25f * (fmaxf(w0, 0.f) + fmaxf(w1, 0.f) + fmaxf(w2, 0.f) + fmaxf(w3, 0.f));
    }

    // staging geometry
    // A (threads 0..127): row ar_=tid>>2, q aq=tid&3
    const int ar_ = tid >> 2;
    const int aq  = tid & 3;
    const float* asrc = ctx_bt + (size_t)(c0 + ar_) * D_ + aq * 4;
    const int awbase = (4 * aq) * ASTR + ar_;
    // B: col bcol=tid>>1 (0..127), k-half bq=tid&1 (8 floats each)
    const int bcol = tid >> 1;
    const int bq   = tid & 1;
    const float* bsrc = ctx_bt + (size_t)(n0 + bcol) * D_ + bq * 8;
    float* bdst = b_s + (bq * 8) * BSTR1 + bcol;

    v2f acc2[8];
    #pragma unroll
    for (int j = 0; j < 8; ++j) acc2[j] = (v2f){0.f, 0.f};

    const int bro = 2 * lane;   // this lane's 2 cols within the tile

    for (int kt = 0; kt < 16; ++kt) {
        __syncthreads();        // previous slice consumed (wbar ready at kt=0)
        {   // B: 16 k-floats of one col -> transposed scalar writes (conflict-free)
            float4 v0 = *(const float4*)(bsrc + kt * 16);
            float4 v1 = *(const float4*)(bsrc + kt * 16 + 4);
            bdst[0 * BSTR1] = v0.x;  bdst[1 * BSTR1] = v0.y;
            bdst[2 * BSTR1] = v0.z;  bdst[3 * BSTR1] = v0.w;
            bdst[4 * BSTR1] = v1.x;  bdst[5 * BSTR1] = v1.y;
            bdst[6 * BSTR1] = v1.z;  bdst[7 * BSTR1] = v1.w;
        }
        if (tid < 128) {
            float4 v  = *(const float4*)(asrc + kt * 16);
            float4 wb = *(const float4*)(wbar_s + kt * 16 + aq * 4);
            a_s[awbase + 0 * ASTR] = v.x * wb.x;
            a_s[awbase + 1 * ASTR] = v.y * wb.y;
            a_s[awbase + 2 * ASTR] = v.z * wb.z;
            a_s[awbase + 3 * ASTR] = v.w * wb.w;
        }
        __syncthreads();
        #pragma unroll
        for (int kk = 0; kk < 16; ++kk) {
            float4 av0 = *(const float4*)(a_s + kk * ASTR + w8);      // wave-uniform broadcast
            float4 av1 = *(const float4*)(a_s + kk * ASTR + w8 + 4);
            v2f bv = *(const v2f*)(b_s + kk * BSTR1 + bro);           // contiguous: conflict-free
            float ar8[8] = {av0.x, av0.y, av0.z, av0.w, av1.x, av1.y, av1.z, av1.w};
            #pragma unroll
            for (int j = 0; j < 8; ++j) {
                v2f a2 = (v2f){ar8[j], ar8[j]};
                acc2[j] += a2 * bv;    // contracted to fma: kk-sequential, bit-exact
            }
        }
    }

    // write 8 rows x 2 cols (v2f, wave-contiguous 512B segments)
    #pragma unroll
    for (int j = 0; j < 8; ++j)
        *(v2f*)(ws + ((size_t)bt * C_ + c0 + w8 + j) * C_ + n0 + bro) = acc2[j];
}

// ========================== Kernel 2: epilogue ===========================
// One wave per attention row: zero out-slice, load row, mask, top-10,
// softmax, spatial, scatter. Write-bound.
extern "C" __global__ __launch_bounds__(256, 2)
void epilogue_k(const float* __restrict__ ws,
                const int* __restrict__ cmask,
                const float* __restrict__ mu_g,
                const float* __restrict__ pr_g,
                float* __restrict__ out)
{
    const int tid  = threadIdx.x;
    const int lane = tid & 63;
    const int wv   = tid >> 6;

    const int blk = blockIdx.x;
    const int bt  = blk >> 7;          // 0..31
    const int rq  = blk & 127;         // 4-row group
    const int b   = bt >> 3;

    // zero this block's output slice: 4 ks x 4 rows x 512 (fire-and-forget;
    // drained at the pre-scatter barrier, covered by the top-k compute)
    {
        const float4 z = make_float4(0.f, 0.f, 0.f, 0.f);
        #pragma unroll
        for (int ks = 0; ks < KS_; ++ks) {
            float* ob = out + ((size_t)(bt * KS_ + ks) * C_ + rq * 4) * C_;
            *(float4*)(ob + (size_t)tid * 4)         = z;
            *(float4*)(ob + (size_t)(tid + 256) * 4) = z;
        }
    }

    const int c  = rq * 4 + wv;        // this wave's row
    const int vr = cmask[b * C_ + c];

    // load row (coalesced b128 x2) + mask
    float row[8];
    {
        const float* wrow = ws + ((size_t)bt * C_ + c) * C_ + lane * 8;
        float4 r0 = *(const float4*)wrow;
        float4 r1 = *(const float4*)(wrow + 4);
        row[0] = r0.x; row[1] = r0.y; row[2] = r0.z; row[3] = r0.w;
        row[4] = r1.x; row[5] = r1.y; row[6] = r1.z; row[7] = r1.w;
        int4 m0 = *(const int4*)(cmask + b * C_ + lane * 8);
        int4 m1 = *(const int4*)(cmask + b * C_ + lane * 8 + 4);
        int em[8] = {m0.x, m0.y, m0.z, m0.w, m1.x, m1.y, m1.z, m1.w};
        #pragma unroll
        for (int i = 0; i < 8; ++i) {
            bool ok = (vr > 0) && (em[i] > 0);
            row[i] = ok ? row[i] : -NEG;
        }
    }

    // top-10 (identical to fused path: stable lexicographic = lax.top_k order)
    float tv[TOPK_];
    int   te[TOPK_];
    unsigned int taken = 0;
    #pragma unroll
    for (int j = 0; j < TOPK_; ++j) {
        float lv = -3.3e38f;
        int   li = 0;
        #pragma unroll
        for (int i = 0; i < 8; ++i) {
            bool better = (!((taken >> i) & 1u)) && (row[i] > lv);
            lv = better ? row[i] : lv;
            li = better ? i : li;
        }
        int le = lane * 8 + li;
        #pragma unroll
        for (int off = 1; off < 64; off <<= 1) {
            float ov = __shfl_xor(lv, off);
            int   oe = __shfl_xor(le, off);
            bool take = (ov > lv) || (ov == lv && oe < le);
            lv = take ? ov : lv;
            le = take ? oe : le;
        }
        tv[j] = lv;
        te[j] = le;
        if ((le >> 3) == lane) taken |= 1u << (le & 7);
    }
    const float mx = tv[0];
    float ssum = 0.f;
    #pragma unroll
    for (int j = 0; j < TOPK_; ++j) ssum += expf(tv[j] - mx);

    float oval = 0.f;
    size_t ooff = 0;
    {
        const int ksq = (lane < 40) ? (lane / 10) : 3;
        const int myj = (lane < 40) ? (lane - (lane / 10) * 10) : 0;
        const float mu = mu_g[ksq];
        const float pr = pr_g[ksq];
        float sps = 0.f, spj = 0.f, tvj = 0.f;
        int ej = 0;
        #pragma unroll
        for (int j = 0; j < TOPK_; ++j) {
            float d = fabsf((float)(te[j] - c));
            d = fminf(d, 160.f) * (1.0f / 160.0f);
            float x  = d - mu;
            float sp = expf(-0.5f * x * x * pr * pr);
            sps += sp;
            if (j == myj) { spj = sp; tvj = tv[j]; ej = te[j]; }
        }
        oval = (expf(tvj - mx) / ssum) * (spj / sps);
        ooff = ((size_t)(bt * KS_ + ksq) * C_ + c) * C_ + ej;
    }

    __syncthreads();   // drain zero-stores (overlapped by compute above)
    if (lane < 40) out[ooff] = oval;
}

// ===================== Fallback: fused kernel (R6) =======================
#define BSTR 516
extern "C" __global__ __launch_bounds__(256, 2)
void graph_learner(const float* __restrict__ ctx,
                   const int* __restrict__ cmask,
                   const float* __restrict__ W,
                   const float* __restrict__ mu_g,
                   const float* __restrict__ pr_g,
                   float* __restrict__ out)
{
    __shared__ __align__(16) float wbar_s[D_];
    __shared__ __align__(16) float a_s[16 * ASTR];
    __shared__ __align__(16) float b_s[16 * BSTR];
    __shared__ __align__(8)  float res_s[2560];
    __shared__ unsigned int vmask_s[16];

    const int tid  = threadIdx.x;
    const int lane = tid & 63;
    const int wv   = tid >> 6;
    const int w8   = wv * 8;

    const int blk = blockIdx.x;
    const int bt  = (blk & 7) * 4 + ((blk >> 3) & 3);
    const int c0  = (blk >> 5) * 32;
    const int b   = bt >> 3;

    const float* ctx_bt = ctx + (size_t)bt * (C_ * D_);
    const int*   mask_b = cmask + b * C_;

    {
        float w0 = W[tid], w1 = W[D_ + tid], w2 = W[2 * D_ + tid], w3 = W[3 * D_ + tid];
        wbar_s[tid] = 0.25f * (fmaxf(w0, 0.f) + fmaxf(w1, 0.f) + fmaxf(w2, 0.f) + fmaxf(w3, 0.f));
    }
    if (tid < 16) {
        unsigned int m = 0;
        for (int i = 0; i < 32; ++i)
            m |= (mask_b[tid * 32 + i] > 0 ? 1u : 0u) << i;
        vmask_s[tid] = m;
    }

    const int brow = tid >> 2;
    const int bq   = tid & 3;
    const float* bsrc = ctx_bt + (size_t)brow * D_ + bq * 4;
    const int bwbase = (4 * bq) * BSTR + 4 * csw2(brow >> 2) + (brow & 3);
    const int ar_ = tid >> 2;
    const int aq  = tid & 3;
    const float* asrc = ctx_bt + (size_t)(c0 + ar_) * D_ + aq * 4;
    const int awbase = (4 * aq) * ASTR + ar_;
    const int bc0 = 4 * csw2(2 * lane);
    const int bc1 = 4 * csw2(2 * lane + 1);

    v2f acc2[8][4];
    #pragma unroll
    for (int j = 0; j < 8; ++j)
        #pragma unroll
        for (int t = 0; t < 4; ++t) acc2[j][t] = (v2f){0.f, 0.f};

    for (int kt = 0; kt < 16; ++kt) {
        __syncthreads();
        #pragma unroll
        for (int i = 0; i < 8; ++i) {
            float4 v = *(const float4*)(bsrc + (size_t)i * 64 * D_ + kt * 16);
            b_s[bwbase + 0 * BSTR + i * 64] = v.x;
            b_s[bwbase + 1 * BSTR + i * 64] = v.y;
            b_s[bwbase + 2 * BSTR + i * 64] = v.z;
            b_s[bwbase + 3 * BSTR + i * 64] = v.w;
        }
        if (tid < 128) {
            float4 v  = *(const float4*)(asrc + kt * 16);
            float4 wb = *(const float4*)(wbar_s + kt * 16 + aq * 4);
            a_s[awbase + 0 * ASTR] = v.x * wb.x;
            a_s[awbase + 1 * ASTR] = v.y * wb.y;
            a_s[awbase + 2 * ASTR] = v.z * wb.z;
            a_s[awbase + 3 * ASTR] = v.w * wb.w;
        }
        __syncthreads();
        #pragma unroll
        for (int kk = 0; kk < 16; ++kk) {
            float4 av0 = *(const float4*)(a_s + kk * ASTR + w8);
            float4 av1 = *(const float4*)(a_s + kk * ASTR + w8 + 4);
            float4 bv0 = *(const float4*)(b_s + kk * BSTR + bc0);
            float4 bv1 = *(const float4*)(b_s + kk * BSTR + bc1);
            v2f b20 = (v2f){bv0.x, bv0.y};
            v2f b21 = (v2f){bv0.z, bv0.w};
            v2f b22 = (v2f){bv1.x, bv1.y};
            v2f b23 = (v2f){bv1.z, bv1.w};
            float ar8[8] = {av0.x, av0.y, av0.z, av0.w, av1.x, av1.y, av1.z, av1.w};
            #pragma unroll
            for (int j = 0; j < 8; ++j) {
                v2f a2 = (v2f){ar8[j], ar8[j]};
                asm("v_pk_fma_f32 %0, %1, %2, %0" : "+v"(acc2[j][0]) : "v"(a2), "v"(b20));
                asm("v_pk_fma_f32 %0, %1, %2, %0" : "+v"(acc2[j][1]) : "v"(a2), "v"(b21));
                asm("v_pk_fma_f32 %0, %1, %2, %0" : "+v"(acc2[j][2]) : "v"(a2), "v"(b22));
                asm("v_pk_fma_f32 %0, %1, %2, %0" : "+v"(acc2[j][3]) : "v"(a2), "v"(b23));
            }
        }
    }

    {
        const float4 z = make_float4(0.f, 0.f, 0.f, 0.f);
        #pragma unroll
        for (int ks = 0; ks < KS_; ++ks) {
            float* ob = out + ((size_t)(bt * KS_ + ks) * C_ + c0) * C_;
            #pragma unroll
            for (int i = 0; i < 16; ++i)
                *(float4*)(ob + (size_t)(tid + i * 256) * 4) = z;
        }
    }

    const unsigned int em8 = (vmask_s[lane >> 2] >> ((lane & 3) * 8)) & 0xffu;
    const float mu0 = mu_g[0], mu1 = mu_g[1], mu2 = mu_g[2], mu3 = mu_g[3];
    const float pr0 = pr_g[0], pr1 = pr_g[1], pr2 = pr_g[2], pr3 = pr_g[3];

    #pragma unroll
    for (int jr = 0; jr < 8; ++jr) {
        const int c  = c0 + w8 + jr;
        const int vr = mask_b[c];
        float row[8];
        #pragma unroll
        for (int t = 0; t < 4; ++t) { row[2 * t] = acc2[jr][t].x; row[2 * t + 1] = acc2[jr][t].y; }
        #pragma unroll
        for (int i = 0; i < 8; ++i) {
            bool ok = (vr > 0) && ((em8 >> i) & 1u);
            row[i] = ok ? row[i] : -NEG;
        }
        float tv[TOPK_];
        int   te[TOPK_];
        unsigned int taken = 0;
        #pragma unroll
        for (int j = 0; j < TOPK_; ++j) {
            float lv = -3.3e38f;
            int   li = 0;
            #pragma unroll
            for (int i = 0; i < 8; ++i) {
                bool better = (!((taken >> i) & 1u)) && (row[i] > lv);
                lv = better ? row[i] : lv;
                li = better ? i : li;
            }
            int le = lane * 8 + li;
            #pragma unroll
            for (int off = 1; off < 64; off <<= 1) {
                float ov = __shfl_xor(lv, off);
                int   oe = __shfl_xor(le, off);
                bool take = (ov > lv) || (ov == lv && oe < le);
                lv = take ? ov : lv;
                le = take ? oe : le;
            }
            tv[j] = lv;
            te[j] = le;
            if ((le >> 3) == lane) taken |= 1u << (le & 7);
        }
        const float mx = tv[0];
        float ssum = 0.f;
        #pragma unroll
        for (int j = 0; j < TOPK_; ++j) ssum += expf(tv[j] - mx);

        if (lane < 40) {
            const int ksq = lane / 10;
            const int myj = lane - ksq * 10;
            const float mu = (ksq == 0) ? mu0 : (ksq == 1) ? mu1 : (ksq == 2) ? mu2 : mu3;
            const float pr = (ksq == 0) ? pr0 : (ksq == 1) ? pr1 : (ksq == 2) ? pr2 : pr3;
            float sps = 0.f, spj = 0.f, tvj = 0.f;
            int ej = 0;
            #pragma unroll
            for (int j = 0; j < TOPK_; ++j) {
                float d = fabsf((float)(te[j] - c));
                d = fminf(d, 160.f) * (1.0f / 160.0f);
                float x  = d - mu;
                float sp = expf(-0.5f * x * x * pr * pr);
                sps += sp;
                if (j == myj) { spj = sp; tvj = tv[j]; ej = te[j]; }
            }
            float val = (expf(tvj - mx) / ssum) * (spj / sps);
            int   off = ((bt * KS_ + ksq) * C_ + c) * C_ + ej;
            int   slot = (((wv * 8 + jr) * 40) + lane) * 2;
            res_s[slot]     = val;
            res_s[slot + 1] = __int_as_float(off);
        }
    }

    __syncthreads();
    #pragma unroll
    for (int i = 0; i < 5; ++i) {
        int p = tid * 5 + i;
        float v   = res_s[2 * p];
        int   off = __float_as_int(res_s[2 * p + 1]);
        out[off] = v;
    }
}

extern "C" void kernel_launch(void* const* d_in, const int* in_sizes, int n_in,
                              void* d_out, int out_size, void* d_ws, size_t ws_size,
                              hipStream_t stream) {
    (void)in_sizes; (void)n_in; (void)out_size;
    const float* ctx   = (const float*)d_in[0];
    const int*   cmask = (const int*)d_in[1];
    const float* W     = (const float*)d_in[2];
    const float* mu    = (const float*)d_in[3];
    const float* pr    = (const float*)d_in[4];
    const size_t WS_NEEDED = (size_t)32 * C_ * C_ * sizeof(float);   // 33.5 MB
    if (ws_size >= WS_NEEDED) {
        float* ws = (float*)d_ws;
        gemm_attn<<<dim3(2048), dim3(256), 0, stream>>>(ctx, W, ws);
        epilogue_k<<<dim3(4096), dim3(256), 0, stream>>>(ws, cmask, mu, pr, (float*)d_out);
    } else {
        graph_learner<<<dim3(512), dim3(256), 0, stream>>>(ctx, cmask, W, mu, pr, (float*)d_out);
    }
}

// Round 8
// 104.350 us; speedup vs baseline: 3.8919x; 1.0564x over previous
//
#include <hip/hip_runtime.h>
#include <math.h>

#define C_ 512
#define D_ 256
#define KS_ 4
#define TOPK_ 10
#define NEG 1e20f

typedef float v2f __attribute__((ext_vector_type(2)));
typedef float v4f __attribute__((ext_vector_type(4)));

__device__ __forceinline__ int csw2(int g) { return g ^ ((g >> 3) & 1); }

#define ASTR 36     // a_s row stride: %4==0 -> b128-aligned reads
#define BSTR2 260   // gemm b_s row stride: %4==0 -> b128-aligned contiguous reads

// pk-FMA with A-half broadcast via op_sel (no splat movs).
// LO: both halves use A.lo ; HI: both halves use A.hi. Each 32-bit half is an
// independent IEEE fp32 FMA chain -> kk-sequential accumulation stays bit-exact.
#define PKFMA_LO(ACC, AP, BP) \
    asm("v_pk_fma_f32 %0, %1, %2, %0 op_sel:[0,0,0] op_sel_hi:[0,1,1]" \
        : "+v"(ACC) : "v"(AP), "v"(BP));
#define PKFMA_HI(ACC, AP, BP) \
    asm("v_pk_fma_f32 %0, %1, %2, %0 op_sel:[1,0,0] op_sel_hi:[1,1,1]" \
        : "+v"(ACC) : "v"(AP), "v"(BP));

// ============================ Kernel 1: GEMM =============================
// attention[bt][c][e] -> ws. Tile 32 rows x 256 cols, grid 1024 (4 blocks/CU),
// per-thread 8x4 acc, op_sel pk-FMA. kk-sequential fp32 -> bit-identical.
extern "C" __global__ __launch_bounds__(256, 2)
void gemm_attn(const float* __restrict__ ctx,
               const float* __restrict__ W,
               float* __restrict__ ws)
{
    __shared__ __align__(16) float wbar_s[D_];
    __shared__ __align__(16) float a_s[16 * ASTR];    // [kk][row 0..31] (x wbar)
    __shared__ __align__(16) float b_s[16 * BSTR2];   // [kk][col 0..255]

    const int tid  = threadIdx.x;
    const int lane = tid & 63;
    const int wv   = tid >> 6;
    const int wr   = (wv >> 1) * 16;     // wave row base within tile
    const int wc   = (wv & 1) * 128;     // wave col base within tile
    const int rg   = lane >> 5;          // row-group within wave (0/1)
    const int cg   = lane & 31;          // col-group within wave

    // XCD swizzle: the 32 tiles of one ctx[b,t] panel land on one XCD's L2
    const int blk  = blockIdx.x;
    const int bt   = (blk & 7) * 4 + ((blk >> 3) & 3);   // 0..31
    const int tile = blk >> 5;                           // 0..31
    const int c0   = (tile & 15) * 32;                   // row tile
    const int n0   = (tile >> 4) * 256;                  // col tile

    const float* ctx_bt = ctx + (size_t)bt * (C_ * D_);

    // wbar = mean_p relu(W[p,:])
    {
        float w0 = W[tid], w1 = W[D_ + tid], w2 = W[2 * D_ + tid], w3 = W[3 * D_ + tid];
        wbar_s[tid] = 0.25f * (fmaxf(w0, 0.f) + fmaxf(w1, 0.f) + fmaxf(w2, 0.f) + fmaxf(w3, 0.f));
    }

    // staging geometry
    // B: thread handles col pair (2cp, 2cp+1) x 8 k's (kh half)
    const int cp = tid & 127;
    const int kh = (tid >> 7) * 8;
    const float* bsrc0 = ctx_bt + (size_t)(n0 + 2 * cp) * D_ + kh;
    const float* bsrc1 = bsrc0 + D_;
    float* bdst = b_s + kh * BSTR2 + 2 * cp;
    // A (threads 0..127): row ar_ = tid>>2, quad aq = tid&3
    const int ar_ = tid >> 2;
    const int aq  = tid & 3;
    const float* asrc = ctx_bt + (size_t)(c0 + ar_) * D_ + aq * 4;
    const int awbase = (4 * aq) * ASTR + ar_;
    // compute read bases
    const int abase = wr + rg * 8;
    const int bbase = wc + cg * 4;

    v2f acc2[8][2];
    #pragma unroll
    for (int j = 0; j < 8; ++j) { acc2[j][0] = (v2f){0.f, 0.f}; acc2[j][1] = (v2f){0.f, 0.f}; }

    for (int kt = 0; kt < 16; ++kt) {
        __syncthreads();        // previous slice consumed (wbar ready at kt=0)
        {   // B: 2 cols x 8 k -> b64 writes (contiguous across wave: conflict-free)
            v4f u00 = *(const v4f*)(bsrc0 + kt * 16);
            v4f u01 = *(const v4f*)(bsrc0 + kt * 16 + 4);
            v4f u10 = *(const v4f*)(bsrc1 + kt * 16);
            v4f u11 = *(const v4f*)(bsrc1 + kt * 16 + 4);
            #pragma unroll
            for (int q = 0; q < 4; ++q) {
                *(v2f*)(bdst + (q + 0) * BSTR2) = (v2f){u00[q], u10[q]};
                *(v2f*)(bdst + (q + 4) * BSTR2) = (v2f){u01[q], u11[q]};
            }
        }
        if (tid < 128) {
            v4f v  = *(const v4f*)(asrc + kt * 16);
            v4f wb = *(const v4f*)(wbar_s + kt * 16 + aq * 4);
            a_s[awbase + 0 * ASTR] = v[0] * wb[0];
            a_s[awbase + 1 * ASTR] = v[1] * wb[1];
            a_s[awbase + 2 * ASTR] = v[2] * wb[2];
            a_s[awbase + 3 * ASTR] = v[3] * wb[3];
        }
        __syncthreads();
        #pragma unroll
        for (int kk = 0; kk < 16; ++kk) {
            v4f av0 = *(const v4f*)(a_s + kk * ASTR + abase);        // broadcast (per half-wave)
            v4f av1 = *(const v4f*)(a_s + kk * ASTR + abase + 4);
            v4f bv  = *(const v4f*)(b_s + kk * BSTR2 + bbase);       // contiguous
            v2f a01 = __builtin_shufflevector(av0, av0, 0, 1);
            v2f a23 = __builtin_shufflevector(av0, av0, 2, 3);
            v2f a45 = __builtin_shufflevector(av1, av1, 0, 1);
            v2f a67 = __builtin_shufflevector(av1, av1, 2, 3);
            v2f blo = __builtin_shufflevector(bv, bv, 0, 1);
            v2f bhi = __builtin_shufflevector(bv, bv, 2, 3);
            PKFMA_LO(acc2[0][0], a01, blo)  PKFMA_LO(acc2[0][1], a01, bhi)
            PKFMA_HI(acc2[1][0], a01, blo)  PKFMA_HI(acc2[1][1], a01, bhi)
            PKFMA_LO(acc2[2][0], a23, blo)  PKFMA_LO(acc2[2][1], a23, bhi)
            PKFMA_HI(acc2[3][0], a23, blo)  PKFMA_HI(acc2[3][1], a23, bhi)
            PKFMA_LO(acc2[4][0], a45, blo)  PKFMA_LO(acc2[4][1], a45, bhi)
            PKFMA_HI(acc2[5][0], a45, blo)  PKFMA_HI(acc2[5][1], a45, bhi)
            PKFMA_LO(acc2[6][0], a67, blo)  PKFMA_LO(acc2[6][1], a67, bhi)
            PKFMA_HI(acc2[7][0], a67, blo)  PKFMA_HI(acc2[7][1], a67, bhi)
        }
    }

    // write 8 rows x 4 cols (b128, coalesced 512B per half-wave)
    #pragma unroll
    for (int j = 0; j < 8; ++j) {
        v4f o = __builtin_shufflevector(acc2[j][0], acc2[j][1], 0, 1, 2, 3);
        *(v4f*)(ws + ((size_t)bt * C_ + c0 + wr + rg * 8 + j) * C_ + n0 + bbase) = o;
    }
}

// ========================== Kernel 2: epilogue ===========================
// One wave per attention row: zero out-slice, load row, mask, top-10,
// softmax, spatial, scatter. Write-bound.
extern "C" __global__ __launch_bounds__(256, 2)
void epilogue_k(const float* __restrict__ ws,
                const int* __restrict__ cmask,
                const float* __restrict__ mu_g,
                const float* __restrict__ pr_g,
                float* __restrict__ out)
{
    const int tid  = threadIdx.x;
    const int lane = tid & 63;
    const int wv   = tid >> 6;

    const int blk = blockIdx.x;
    const int bt  = blk >> 7;          // 0..31
    const int rq  = blk & 127;         // 4-row group
    const int b   = bt >> 3;

    // zero this block's output slice: 4 ks x 4 rows x 512 (fire-and-forget;
    // drained at the pre-scatter barrier, covered by the top-k compute)
    {
        const float4 z = make_float4(0.f, 0.f, 0.f, 0.f);
        #pragma unroll
        for (int ks = 0; ks < KS_; ++ks) {
            float* ob = out + ((size_t)(bt * KS_ + ks) * C_ + rq * 4) * C_;
            *(float4*)(ob + (size_t)tid * 4)         = z;
            *(float4*)(ob + (size_t)(tid + 256) * 4) = z;
        }
    }

    const int c  = rq * 4 + wv;        // this wave's row
    const int vr = cmask[b * C_ + c];

    // load row (coalesced b128 x2) + mask
    float row[8];
    {
        const float* wrow = ws + ((size_t)bt * C_ + c) * C_ + lane * 8;
        float4 r0 = *(const float4*)wrow;
        float4 r1 = *(const float4*)(wrow + 4);
        row[0] = r0.x; row[1] = r0.y; row[2] = r0.z; row[3] = r0.w;
        row[4] = r1.x; row[5] = r1.y; row[6] = r1.z; row[7] = r1.w;
        int4 m0 = *(const int4*)(cmask + b * C_ + lane * 8);
        int4 m1 = *(const int4*)(cmask + b * C_ + lane * 8 + 4);
        int em[8] = {m0.x, m0.y, m0.z, m0.w, m1.x, m1.y, m1.z, m1.w};
        #pragma unroll
        for (int i = 0; i < 8; ++i) {
            bool ok = (vr > 0) && (em[i] > 0);
            row[i] = ok ? row[i] : -NEG;
        }
    }

    // top-10 (stable lexicographic = lax.top_k order)
    float tv[TOPK_];
    int   te[TOPK_];
    unsigned int taken = 0;
    #pragma unroll
    for (int j = 0; j < TOPK_; ++j) {
        float lv = -3.3e38f;
        int   li = 0;
        #pragma unroll
        for (int i = 0; i < 8; ++i) {
            bool better = (!((taken >> i) & 1u)) && (row[i] > lv);
            lv = better ? row[i] : lv;
            li = better ? i : li;
        }
        int le = lane * 8 + li;
        #pragma unroll
        for (int off = 1; off < 64; off <<= 1) {
            float ov = __shfl_xor(lv, off);
            int   oe = __shfl_xor(le, off);
            bool take = (ov > lv) || (ov == lv && oe < le);
            lv = take ? ov : lv;
            le = take ? oe : le;
        }
        tv[j] = lv;
        te[j] = le;
        if ((le >> 3) == lane) taken |= 1u << (le & 7);
    }
    const float mx = tv[0];
    float ssum = 0.f;
    #pragma unroll
    for (int j = 0; j < TOPK_; ++j) ssum += expf(tv[j] - mx);

    float oval = 0.f;
    size_t ooff = 0;
    {
        const int ksq = (lane < 40) ? (lane / 10) : 3;
        const int myj = (lane < 40) ? (lane - (lane / 10) * 10) : 0;
        const float mu = mu_g[ksq];
        const float pr = pr_g[ksq];
        float sps = 0.f, spj = 0.f, tvj = 0.f;
        int ej = 0;
        #pragma unroll
        for (int j = 0; j < TOPK_; ++j) {
            float d = fabsf((float)(te[j] - c));
            d = fminf(d, 160.f) * (1.0f / 160.0f);
            float x  = d - mu;
            float sp = expf(-0.5f * x * x * pr * pr);
            sps += sp;
            if (j == myj) { spj = sp; tvj = tv[j]; ej = te[j]; }
        }
        oval = (expf(tvj - mx) / ssum) * (spj / sps);
        ooff = ((size_t)(bt * KS_ + ksq) * C_ + c) * C_ + ej;
    }

    __syncthreads();   // drain zero-stores (overlapped by compute above)
    if (lane < 40) out[ooff] = oval;
}

// ===================== Fallback: fused kernel (R6) =======================
#define BSTR 516
extern "C" __global__ __launch_bounds__(256, 2)
void graph_learner(const float* __restrict__ ctx,
                   const int* __restrict__ cmask,
                   const float* __restrict__ W,
                   const float* __restrict__ mu_g,
                   const float* __restrict__ pr_g,
                   float* __restrict__ out)
{
    __shared__ __align__(16) float wbar_s[D_];
    __shared__ __align__(16) float a_s[16 * ASTR];
    __shared__ __align__(16) float b_s[16 * BSTR];
    __shared__ __align__(8)  float res_s[2560];
    __shared__ unsigned int vmask_s[16];

    const int tid  = threadIdx.x;
    const int lane = tid & 63;
    const int wv   = tid >> 6;
    const int w8   = wv * 8;

    const int blk = blockIdx.x;
    const int bt  = (blk & 7) * 4 + ((blk >> 3) & 3);
    const int c0  = (blk >> 5) * 32;
    const int b   = bt >> 3;

    const float* ctx_bt = ctx + (size_t)bt * (C_ * D_);
    const int*   mask_b = cmask + b * C_;

    {
        float w0 = W[tid], w1 = W[D_ + tid], w2 = W[2 * D_ + tid], w3 = W[3 * D_ + tid];
        wbar_s[tid] = 0.25f * (fmaxf(w0, 0.f) + fmaxf(w1, 0.f) + fmaxf(w2, 0.f) + fmaxf(w3, 0.f));
    }
    if (tid < 16) {
        unsigned int m = 0;
        for (int i = 0; i < 32; ++i)
            m |= (mask_b[tid * 32 + i] > 0 ? 1u : 0u) << i;
        vmask_s[tid] = m;
    }

    const int brow = tid >> 2;
    const int bq   = tid & 3;
    const float* bsrc = ctx_bt + (size_t)brow * D_ + bq * 4;
    const int bwbase = (4 * bq) * BSTR + 4 * csw2(brow >> 2) + (brow & 3);
    const int ar_ = tid >> 2;
    const int aq  = tid & 3;
    const float* asrc = ctx_bt + (size_t)(c0 + ar_) * D_ + aq * 4;
    const int awbase = (4 * aq) * ASTR + ar_;
    const int bc0 = 4 * csw2(2 * lane);
    const int bc1 = 4 * csw2(2 * lane + 1);

    v2f acc2[8][4];
    #pragma unroll
    for (int j = 0; j < 8; ++j)
        #pragma unroll
        for (int t = 0; t < 4; ++t) acc2[j][t] = (v2f){0.f, 0.f};

    for (int kt = 0; kt < 16; ++kt) {
        __syncthreads();
        #pragma unroll
        for (int i = 0; i < 8; ++i) {
            float4 v = *(const float4*)(bsrc + (size_t)i * 64 * D_ + kt * 16);
            b_s[bwbase + 0 * BSTR + i * 64] = v.x;
            b_s[bwbase + 1 * BSTR + i * 64] = v.y;
            b_s[bwbase + 2 * BSTR + i * 64] = v.z;
            b_s[bwbase + 3 * BSTR + i * 64] = v.w;
        }
        if (tid < 128) {
            float4 v  = *(const float4*)(asrc + kt * 16);
            float4 wb = *(const float4*)(wbar_s + kt * 16 + aq * 4);
            a_s[awbase + 0 * ASTR] = v.x * wb.x;
            a_s[awbase + 1 * ASTR] = v.y * wb.y;
            a_s[awbase + 2 * ASTR] = v.z * wb.z;
            a_s[awbase + 3 * ASTR] = v.w * wb.w;
        }
        __syncthreads();
        #pragma unroll
        for (int kk = 0; kk < 16; ++kk) {
            float4 av0 = *(const float4*)(a_s + kk * ASTR + w8);
            float4 av1 = *(const float4*)(a_s + kk * ASTR + w8 + 4);
            float4 bv0 = *(const float4*)(b_s + kk * BSTR + bc0);
            float4 bv1 = *(const float4*)(b_s + kk * BSTR + bc1);
            v2f b20 = (v2f){bv0.x, bv0.y};
            v2f b21 = (v2f){bv0.z, bv0.w};
            v2f b22 = (v2f){bv1.x, bv1.y};
            v2f b23 = (v2f){bv1.z, bv1.w};
            float ar8[8] = {av0.x, av0.y, av0.z, av0.w, av1.x, av1.y, av1.z, av1.w};
            #pragma unroll
            for (int j = 0; j < 8; ++j) {
                v2f a2 = (v2f){ar8[j], ar8[j]};
                asm("v_pk_fma_f32 %0, %1, %2, %0" : "+v"(acc2[j][0]) : "v"(a2), "v"(b20));
                asm("v_pk_fma_f32 %0, %1, %2, %0" : "+v"(acc2[j][1]) : "v"(a2), "v"(b21));
                asm("v_pk_fma_f32 %0, %1, %2, %0" : "+v"(acc2[j][2]) : "v"(a2), "v"(b22));
                asm("v_pk_fma_f32 %0, %1, %2, %0" : "+v"(acc2[j][3]) : "v"(a2), "v"(b23));
            }
        }
    }

    {
        const float4 z = make_float4(0.f, 0.f, 0.f, 0.f);
        #pragma unroll
        for (int ks = 0; ks < KS_; ++ks) {
            float* ob = out + ((size_t)(bt * KS_ + ks) * C_ + c0) * C_;
            #pragma unroll
            for (int i = 0; i < 16; ++i)
                *(float4*)(ob + (size_t)(tid + i * 256) * 4) = z;
        }
    }

    const unsigned int em8 = (vmask_s[lane >> 2] >> ((lane & 3) * 8)) & 0xffu;
    const float mu0 = mu_g[0], mu1 = mu_g[1], mu2 = mu_g[2], mu3 = mu_g[3];
    const float pr0 = pr_g[0], pr1 = pr_g[1], pr2 = pr_g[2], pr3 = pr_g[3];

    #pragma unroll
    for (int jr = 0; jr < 8; ++jr) {
        const int c  = c0 + w8 + jr;
        const int vr = mask_b[c];
        float row[8];
        #pragma unroll
        for (int t = 0; t < 4; ++t) { row[2 * t] = acc2[jr][t].x; row[2 * t + 1] = acc2[jr][t].y; }
        #pragma unroll
        for (int i = 0; i < 8; ++i) {
            bool ok = (vr > 0) && ((em8 >> i) & 1u);
            row[i] = ok ? row[i] : -NEG;
        }
        float tv[TOPK_];
        int   te[TOPK_];
        unsigned int taken = 0;
        #pragma unroll
        for (int j = 0; j < TOPK_; ++j) {
            float lv = -3.3e38f;
            int   li = 0;
            #pragma unroll
            for (int i = 0; i < 8; ++i) {
                bool better = (!((taken >> i) & 1u)) && (row[i] > lv);
                lv = better ? row[i] : lv;
                li = better ? i : li;
            }
            int le = lane * 8 + li;
            #pragma unroll
            for (int off = 1; off < 64; off <<= 1) {
                float ov = __shfl_xor(lv, off);
                int   oe = __shfl_xor(le, off);
                bool take = (ov > lv) || (ov == lv && oe < le);
                lv = take ? ov : lv;
                le = take ? oe : le;
            }
            tv[j] = lv;
            te[j] = le;
            if ((le >> 3) == lane) taken |= 1u << (le & 7);
        }
        const float mx = tv[0];
        float ssum = 0.f;
        #pragma unroll
        for (int j = 0; j < TOPK_; ++j) ssum += expf(tv[j] - mx);

        if (lane < 40) {
            const int ksq = lane / 10;
            const int myj = lane - ksq * 10;
            const float mu = (ksq == 0) ? mu0 : (ksq == 1) ? mu1 : (ksq == 2) ? mu2 : mu3;
            const float pr = (ksq == 0) ? pr0 : (ksq == 1) ? pr1 : (ksq == 2) ? pr2 : pr3;
            float sps = 0.f, spj = 0.f, tvj = 0.f;
            int ej = 0;
            #pragma unroll
            for (int j = 0; j < TOPK_; ++j) {
                float d = fabsf((float)(te[j] - c));
                d = fminf(d, 160.f) * (1.0f / 160.0f);
                float x  = d - mu;
                float sp = expf(-0.5f * x * x * pr * pr);
                sps += sp;
                if (j == myj) { spj = sp; tvj = tv[j]; ej = te[j]; }
            }
            float val = (expf(tvj - mx) / ssum) * (spj / sps);
            int   off = ((bt * KS_ + ksq) * C_ + c) * C_ + ej;
            int   slot = (((wv * 8 + jr) * 40) + lane) * 2;
            res_s[slot]     = val;
            res_s[slot + 1] = __int_as_float(off);
        }
    }

    __syncthreads();
    #pragma unroll
    for (int i = 0; i < 5; ++i) {
        int p = tid * 5 + i;
        float v   = res_s[2 * p];
        int   off = __float_as_int(res_s[2 * p + 1]);
        out[off] = v;
    }
}

extern "C" void kernel_launch(void* const* d_in, const int* in_sizes, int n_in,
                              void* d_out, int out_size, void* d_ws, size_t ws_size,
                              hipStream_t stream) {
    (void)in_sizes; (void)n_in; (void)out_size;
    const float* ctx   = (const float*)d_in[0];
    const int*   cmask = (const int*)d_in[1];
    const float* W     = (const float*)d_in[2];
    const float* mu    = (const float*)d_in[3];
    const float* pr    = (const float*)d_in[4];
    const size_t WS_NEEDED = (size_t)32 * C_ * C_ * sizeof(float);   // 33.5 MB
    if (ws_size >= WS_NEEDED) {
        float* ws = (float*)d_ws;
        gemm_attn<<<dim3(1024), dim3(256), 0, stream>>>(ctx, W, ws);
        epilogue_k<<<dim3(4096), dim3(256), 0, stream>>>(ws, cmask, mu, pr, (float*)d_out);
    } else {
        graph_learner<<<dim3(512), dim3(256), 0, stream>>>(ctx, cmask, W, mu, pr, (float*)d_out);
    }
}

// Round 9
// 96.655 us; speedup vs baseline: 4.2018x; 1.0796x over previous
//
#include <hip/hip_runtime.h>
#include <math.h>

#define C_ 512
#define D_ 256
#define KS_ 4
#define TOPK_ 10
#define NEG 1e20f

typedef float v2f __attribute__((ext_vector_type(2)));
typedef float v4f __attribute__((ext_vector_type(4)));

__device__ __forceinline__ int csw2(int g) { return g ^ ((g >> 3) & 1); }

#define ASTR 36     // a_s row stride: %4==0 -> b128-aligned reads; 36%32=4 -> transposed writes conflict-free
#define BSTR2 260   // b_s row stride: %4==0 -> b128 reads aligned; 260%32=4 -> transposed writes 2-way max

// pk-FMA with A-half broadcast via op_sel (no splat movs). Each 32-bit half is an
// independent IEEE fp32 FMA chain -> kk-sequential accumulation stays bit-exact.
#define PKFMA_LO(ACC, AP, BP) \
    asm("v_pk_fma_f32 %0, %1, %2, %0 op_sel:[0,0,0] op_sel_hi:[0,1,1]" \
        : "+v"(ACC) : "v"(AP), "v"(BP));
#define PKFMA_HI(ACC, AP, BP) \
    asm("v_pk_fma_f32 %0, %1, %2, %0 op_sel:[1,0,0] op_sel_hi:[1,1,1]" \
        : "+v"(ACC) : "v"(AP), "v"(BP));

// ============================ Kernel 1: GEMM =============================
// attention[bt][c][e] -> ws. Tile 32 rows x 256 cols, grid 1024 (4 blocks/CU),
// per-thread 8x4 acc. Coalesced 64B-group staging + register prefetch across
// the barrier (acc is only 32 VGPR -> prefetch fits under the 128 cap).
extern "C" __global__ __launch_bounds__(256, 2)
void gemm_attn(const float* __restrict__ ctx,
               const float* __restrict__ W,
               float* __restrict__ ws)
{
    __shared__ __align__(16) float wbar_s[D_];
    __shared__ __align__(16) float a_s[16 * ASTR];    // [kk][row 0..31] (x wbar)
    __shared__ __align__(16) float b_s[16 * BSTR2];   // [kk][col 0..255]

    const int tid  = threadIdx.x;
    const int lane = tid & 63;
    const int wv   = tid >> 6;
    const int wr   = (wv >> 1) * 16;     // wave row base within tile
    const int wc   = (wv & 1) * 128;     // wave col base within tile
    const int rg   = lane >> 5;          // row-group within wave (0/1)
    const int cg   = lane & 31;          // col-group within wave

    // XCD swizzle: the 32 tiles of one ctx[b,t] panel land on one XCD's L2
    const int blk  = blockIdx.x;
    const int bt   = (blk & 7) * 4 + ((blk >> 3) & 3);   // 0..31
    const int tile = blk >> 5;                           // 0..31
    const int c0   = (tile & 15) * 32;                   // row tile
    const int n0   = (tile >> 4) * 256;                  // col tile

    const float* ctx_bt = ctx + (size_t)bt * (C_ * D_);

    // wbar = mean_p relu(W[p,:])
    {
        float w0 = W[tid], w1 = W[D_ + tid], w2 = W[2 * D_ + tid], w3 = W[3 * D_ + tid];
        wbar_s[tid] = 0.25f * (fmaxf(w0, 0.f) + fmaxf(w1, 0.f) + fmaxf(w2, 0.f) + fmaxf(w3, 0.f));
    }

    // ---- staging geometry: 4-lane groups read contiguous 64B of one row ----
    // B: ch = tid + 256*i, col = ch>>2 (0..255), quad = ch&3
    const int bcol = tid >> 2;           // col for i=0 (cols 0..63); i adds 64
    const int bq   = tid & 3;
    const float* bsrc = ctx_bt + (size_t)(n0 + bcol) * D_ + bq * 4;   // + i*64*D_ + kt*16
    float* bdst = b_s + (4 * bq) * BSTR2 + bcol;                       // + j*BSTR2 + i*64
    // A (threads 0..127): row ar = tid>>2 (0..31), quad aq
    const int ar_ = tid >> 2;
    const int aq  = tid & 3;
    const float* asrc = ctx_bt + (size_t)(c0 + ar_) * D_ + aq * 4;
    const int awbase = (4 * aq) * ASTR + ar_;
    // compute read bases
    const int abase = wr + rg * 8;
    const int bbase = wc + cg * 4;

    v2f acc2[8][2];
    #pragma unroll
    for (int j = 0; j < 8; ++j) { acc2[j][0] = (v2f){0.f, 0.f}; acc2[j][1] = (v2f){0.f, 0.f}; }

    // prologue: load k-slice 0 into registers
    v4f B0, B1, B2, B3, A0;
    B0 = *(const v4f*)(bsrc + (size_t)0 * 64 * D_);
    B1 = *(const v4f*)(bsrc + (size_t)1 * 64 * D_);
    B2 = *(const v4f*)(bsrc + (size_t)2 * 64 * D_);
    B3 = *(const v4f*)(bsrc + (size_t)3 * 64 * D_);
    if (tid < 128) A0 = *(const v4f*)asrc;

    for (int kt = 0; kt < 16; ++kt) {
        __syncthreads();        // previous slice fully consumed (wbar ready at kt=0)
        // write staged registers -> LDS (transposed; 2-way max conflicts)
        #pragma unroll
        for (int j = 0; j < 4; ++j) {
            bdst[j * BSTR2 + 0 * 64] = B0[j];
            bdst[j * BSTR2 + 1 * 64] = B1[j];
            bdst[j * BSTR2 + 2 * 64] = B2[j];
            bdst[j * BSTR2 + 3 * 64] = B3[j];
        }
        if (tid < 128) {
            v4f wb = *(const v4f*)(wbar_s + kt * 16 + aq * 4);
            a_s[awbase + 0 * ASTR] = A0[0] * wb[0];
            a_s[awbase + 1 * ASTR] = A0[1] * wb[1];
            a_s[awbase + 2 * ASTR] = A0[2] * wb[2];
            a_s[awbase + 3 * ASTR] = A0[3] * wb[3];
        }
        __syncthreads();        // slice ready
        if (kt < 15) {          // T14: issue next-slice loads; latency hides under compute
            const float* nb = bsrc + (kt + 1) * 16;
            B0 = *(const v4f*)(nb + (size_t)0 * 64 * D_);
            B1 = *(const v4f*)(nb + (size_t)1 * 64 * D_);
            B2 = *(const v4f*)(nb + (size_t)2 * 64 * D_);
            B3 = *(const v4f*)(nb + (size_t)3 * 64 * D_);
            if (tid < 128) A0 = *(const v4f*)(asrc + (kt + 1) * 16);
        }
        #pragma unroll
        for (int kk = 0; kk < 16; ++kk) {
            v4f av0 = *(const v4f*)(a_s + kk * ASTR + abase);        // broadcast (2 addrs/wave)
            v4f av1 = *(const v4f*)(a_s + kk * ASTR + abase + 4);
            v4f bv  = *(const v4f*)(b_s + kk * BSTR2 + bbase);       // contiguous
            v2f a01 = __builtin_shufflevector(av0, av0, 0, 1);
            v2f a23 = __builtin_shufflevector(av0, av0, 2, 3);
            v2f a45 = __builtin_shufflevector(av1, av1, 0, 1);
            v2f a67 = __builtin_shufflevector(av1, av1, 2, 3);
            v2f blo = __builtin_shufflevector(bv, bv, 0, 1);
            v2f bhi = __builtin_shufflevector(bv, bv, 2, 3);
            PKFMA_LO(acc2[0][0], a01, blo)  PKFMA_LO(acc2[0][1], a01, bhi)
            PKFMA_HI(acc2[1][0], a01, blo)  PKFMA_HI(acc2[1][1], a01, bhi)
            PKFMA_LO(acc2[2][0], a23, blo)  PKFMA_LO(acc2[2][1], a23, bhi)
            PKFMA_HI(acc2[3][0], a23, blo)  PKFMA_HI(acc2[3][1], a23, bhi)
            PKFMA_LO(acc2[4][0], a45, blo)  PKFMA_LO(acc2[4][1], a45, bhi)
            PKFMA_HI(acc2[5][0], a45, blo)  PKFMA_HI(acc2[5][1], a45, bhi)
            PKFMA_LO(acc2[6][0], a67, blo)  PKFMA_LO(acc2[6][1], a67, bhi)
            PKFMA_HI(acc2[7][0], a67, blo)  PKFMA_HI(acc2[7][1], a67, bhi)
        }
    }

    // write 8 rows x 4 cols (b128, coalesced 512B per half-wave)
    #pragma unroll
    for (int j = 0; j < 8; ++j) {
        v4f o = __builtin_shufflevector(acc2[j][0], acc2[j][1], 0, 1, 2, 3);
        *(v4f*)(ws + ((size_t)bt * C_ + c0 + wr + rg * 8 + j) * C_ + n0 + bbase) = o;
    }
}

// ========================== Kernel 2: epilogue ===========================
extern "C" __global__ __launch_bounds__(256, 2)
void epilogue_k(const float* __restrict__ ws,
                const int* __restrict__ cmask,
                const float* __restrict__ mu_g,
                const float* __restrict__ pr_g,
                float* __restrict__ out)
{
    const int tid  = threadIdx.x;
    const int lane = tid & 63;
    const int wv   = tid >> 6;

    const int blk = blockIdx.x;
    const int bt  = blk >> 7;          // 0..31
    const int rq  = blk & 127;         // 4-row group
    const int b   = bt >> 3;

    // zero this block's output slice (fire-and-forget; drained at the barrier
    // below, covered by the top-k compute)
    {
        const float4 z = make_float4(0.f, 0.f, 0.f, 0.f);
        #pragma unroll
        for (int ks = 0; ks < KS_; ++ks) {
            float* ob = out + ((size_t)(bt * KS_ + ks) * C_ + rq * 4) * C_;
            *(float4*)(ob + (size_t)tid * 4)         = z;
            *(float4*)(ob + (size_t)(tid + 256) * 4) = z;
        }
    }

    const int c  = rq * 4 + wv;        // this wave's row
    const int vr = cmask[b * C_ + c];

    float row[8];
    {
        const float* wrow = ws + ((size_t)bt * C_ + c) * C_ + lane * 8;
        float4 r0 = *(const float4*)wrow;
        float4 r1 = *(const float4*)(wrow + 4);
        row[0] = r0.x; row[1] = r0.y; row[2] = r0.z; row[3] = r0.w;
        row[4] = r1.x; row[5] = r1.y; row[6] = r1.z; row[7] = r1.w;
        int4 m0 = *(const int4*)(cmask + b * C_ + lane * 8);
        int4 m1 = *(const int4*)(cmask + b * C_ + lane * 8 + 4);
        int em[8] = {m0.x, m0.y, m0.z, m0.w, m1.x, m1.y, m1.z, m1.w};
        #pragma unroll
        for (int i = 0; i < 8; ++i) {
            bool ok = (vr > 0) && (em[i] > 0);
            row[i] = ok ? row[i] : -NEG;
        }
    }

    float tv[TOPK_];
    int   te[TOPK_];
    unsigned int taken = 0;
    #pragma unroll
    for (int j = 0; j < TOPK_; ++j) {
        float lv = -3.3e38f;
        int   li = 0;
        #pragma unroll
        for (int i = 0; i < 8; ++i) {
            bool better = (!((taken >> i) & 1u)) && (row[i] > lv);
            lv = better ? row[i] : lv;
            li = better ? i : li;
        }
        int le = lane * 8 + li;
        #pragma unroll
        for (int off = 1; off < 64; off <<= 1) {
            float ov = __shfl_xor(lv, off);
            int   oe = __shfl_xor(le, off);
            bool take = (ov > lv) || (ov == lv && oe < le);
            lv = take ? ov : lv;
            le = take ? oe : le;
        }
        tv[j] = lv;
        te[j] = le;
        if ((le >> 3) == lane) taken |= 1u << (le & 7);
    }
    const float mx = tv[0];
    float ssum = 0.f;
    #pragma unroll
    for (int j = 0; j < TOPK_; ++j) ssum += expf(tv[j] - mx);

    float oval = 0.f;
    size_t ooff = 0;
    {
        const int ksq = (lane < 40) ? (lane / 10) : 3;
        const int myj = (lane < 40) ? (lane - (lane / 10) * 10) : 0;
        const float mu = mu_g[ksq];
        const float pr = pr_g[ksq];
        float sps = 0.f, spj = 0.f, tvj = 0.f;
        int ej = 0;
        #pragma unroll
        for (int j = 0; j < TOPK_; ++j) {
            float d = fabsf((float)(te[j] - c));
            d = fminf(d, 160.f) * (1.0f / 160.0f);
            float x  = d - mu;
            float sp = expf(-0.5f * x * x * pr * pr);
            sps += sp;
            if (j == myj) { spj = sp; tvj = tv[j]; ej = te[j]; }
        }
        oval = (expf(tvj - mx) / ssum) * (spj / sps);
        ooff = ((size_t)(bt * KS_ + ksq) * C_ + c) * C_ + ej;
    }

    __syncthreads();   // drain zero-stores (overlapped by compute above)
    if (lane < 40) out[ooff] = oval;
}

// ===================== Fallback: fused kernel (R6) =======================
#define BSTR 516
extern "C" __global__ __launch_bounds__(256, 2)
void graph_learner(const float* __restrict__ ctx,
                   const int* __restrict__ cmask,
                   const float* __restrict__ W,
                   const float* __restrict__ mu_g,
                   const float* __restrict__ pr_g,
                   float* __restrict__ out)
{
    __shared__ __align__(16) float wbar_s[D_];
    __shared__ __align__(16) float a_s[16 * ASTR];
    __shared__ __align__(16) float b_s[16 * BSTR];
    __shared__ __align__(8)  float res_s[2560];
    __shared__ unsigned int vmask_s[16];

    const int tid  = threadIdx.x;
    const int lane = tid & 63;
    const int wv   = tid >> 6;
    const int w8   = wv * 8;

    const int blk = blockIdx.x;
    const int bt  = (blk & 7) * 4 + ((blk >> 3) & 3);
    const int c0  = (blk >> 5) * 32;
    const int b   = bt >> 3;

    const float* ctx_bt = ctx + (size_t)bt * (C_ * D_);
    const int*   mask_b = cmask + b * C_;

    {
        float w0 = W[tid], w1 = W[D_ + tid], w2 = W[2 * D_ + tid], w3 = W[3 * D_ + tid];
        wbar_s[tid] = 0.25f * (fmaxf(w0, 0.f) + fmaxf(w1, 0.f) + fmaxf(w2, 0.f) + fmaxf(w3, 0.f));
    }
    if (tid < 16) {
        unsigned int m = 0;
        for (int i = 0; i < 32; ++i)
            m |= (mask_b[tid * 32 + i] > 0 ? 1u : 0u) << i;
        vmask_s[tid] = m;
    }

    const int brow = tid >> 2;
    const int bq   = tid & 3;
    const float* bsrc = ctx_bt + (size_t)brow * D_ + bq * 4;
    const int bwbase = (4 * bq) * BSTR + 4 * csw2(brow >> 2) + (brow & 3);
    const int ar_ = tid >> 2;
    const int aq  = tid & 3;
    const float* asrc = ctx_bt + (size_t)(c0 + ar_) * D_ + aq * 4;
    const int awbase = (4 * aq) * ASTR + ar_;
    const int bc0 = 4 * csw2(2 * lane);
    const int bc1 = 4 * csw2(2 * lane + 1);

    v2f acc2[8][4];
    #pragma unroll
    for (int j = 0; j < 8; ++j)
        #pragma unroll
        for (int t = 0; t < 4; ++t) acc2[j][t] = (v2f){0.f, 0.f};

    for (int kt = 0; kt < 16; ++kt) {
        __syncthreads();
        #pragma unroll
        for (int i = 0; i < 8; ++i) {
            float4 v = *(const float4*)(bsrc + (size_t)i * 64 * D_ + kt * 16);
            b_s[bwbase + 0 * BSTR + i * 64] = v.x;
            b_s[bwbase + 1 * BSTR + i * 64] = v.y;
            b_s[bwbase + 2 * BSTR + i * 64] = v.z;
            b_s[bwbase + 3 * BSTR + i * 64] = v.w;
        }
        if (tid < 128) {
            float4 v  = *(const float4*)(asrc + kt * 16);
            float4 wb = *(const float4*)(wbar_s + kt * 16 + aq * 4);
            a_s[awbase + 0 * ASTR] = v.x * wb.x;
            a_s[awbase + 1 * ASTR] = v.y * wb.y;
            a_s[awbase + 2 * ASTR] = v.z * wb.z;
            a_s[awbase + 3 * ASTR] = v.w * wb.w;
        }
        __syncthreads();
        #pragma unroll
        for (int kk = 0; kk < 16; ++kk) {
            float4 av0 = *(const float4*)(a_s + kk * ASTR + w8);
            float4 av1 = *(const float4*)(a_s + kk * ASTR + w8 + 4);
            float4 bv0 = *(const float4*)(b_s + kk * BSTR + bc0);
            float4 bv1 = *(const float4*)(b_s + kk * BSTR + bc1);
            v2f b20 = (v2f){bv0.x, bv0.y};
            v2f b21 = (v2f){bv0.z, bv0.w};
            v2f b22 = (v2f){bv1.x, bv1.y};
            v2f b23 = (v2f){bv1.z, bv1.w};
            float ar8[8] = {av0.x, av0.y, av0.z, av0.w, av1.x, av1.y, av1.z, av1.w};
            #pragma unroll
            for (int j = 0; j < 8; ++j) {
                v2f a2 = (v2f){ar8[j], ar8[j]};
                asm("v_pk_fma_f32 %0, %1, %2, %0" : "+v"(acc2[j][0]) : "v"(a2), "v"(b20));
                asm("v_pk_fma_f32 %0, %1, %2, %0" : "+v"(acc2[j][1]) : "v"(a2), "v"(b21));
                asm("v_pk_fma_f32 %0, %1, %2, %0" : "+v"(acc2[j][2]) : "v"(a2), "v"(b22));
                asm("v_pk_fma_f32 %0, %1, %2, %0" : "+v"(acc2[j][3]) : "v"(a2), "v"(b23));
            }
        }
    }

    {
        const float4 z = make_float4(0.f, 0.f, 0.f, 0.f);
        #pragma unroll
        for (int ks = 0; ks < KS_; ++ks) {
            float* ob = out + ((size_t)(bt * KS_ + ks) * C_ + c0) * C_;
            #pragma unroll
            for (int i = 0; i < 16; ++i)
                *(float4*)(ob + (size_t)(tid + i * 256) * 4) = z;
        }
    }

    const unsigned int em8 = (vmask_s[lane >> 2] >> ((lane & 3) * 8)) & 0xffu;
    const float mu0 = mu_g[0], mu1 = mu_g[1], mu2 = mu_g[2], mu3 = mu_g[3];
    const float pr0 = pr_g[0], pr1 = pr_g[1], pr2 = pr_g[2], pr3 = pr_g[3];

    #pragma unroll
    for (int jr = 0; jr < 8; ++jr) {
        const int c  = c0 + w8 + jr;
        const int vr = mask_b[c];
        float row[8];
        #pragma unroll
        for (int t = 0; t < 4; ++t) { row[2 * t] = acc2[jr][t].x; row[2 * t + 1] = acc2[jr][t].y; }
        #pragma unroll
        for (int i = 0; i < 8; ++i) {
            bool ok = (vr > 0) && ((em8 >> i) & 1u);
            row[i] = ok ? row[i] : -NEG;
        }
        float tv[TOPK_];
        int   te[TOPK_];
        unsigned int taken = 0;
        #pragma unroll
        for (int j = 0; j < TOPK_; ++j) {
            float lv = -3.3e38f;
            int   li = 0;
            #pragma unroll
            for (int i = 0; i < 8; ++i) {
                bool better = (!((taken >> i) & 1u)) && (row[i] > lv);
                lv = better ? row[i] : lv;
                li = better ? i : li;
            }
            int le = lane * 8 + li;
            #pragma unroll
            for (int off = 1; off < 64; off <<= 1) {
                float ov = __shfl_xor(lv, off);
                int   oe = __shfl_xor(le, off);
                bool take = (ov > lv) || (ov == lv && oe < le);
                lv = take ? ov : lv;
                le = take ? oe : le;
            }
            tv[j] = lv;
            te[j] = le;
            if ((le >> 3) == lane) taken |= 1u << (le & 7);
        }
        const float mx = tv[0];
        float ssum = 0.f;
        #pragma unroll
        for (int j = 0; j < TOPK_; ++j) ssum += expf(tv[j] - mx);

        if (lane < 40) {
            const int ksq = lane / 10;
            const int myj = lane - ksq * 10;
            const float mu = (ksq == 0) ? mu0 : (ksq == 1) ? mu1 : (ksq == 2) ? mu2 : mu3;
            const float pr = (ksq == 0) ? pr0 : (ksq == 1) ? pr1 : (ksq == 2) ? pr2 : pr3;
            float sps = 0.f, spj = 0.f, tvj = 0.f;
            int ej = 0;
            #pragma unroll
            for (int j = 0; j < TOPK_; ++j) {
                float d = fabsf((float)(te[j] - c));
                d = fminf(d, 160.f) * (1.0f / 160.0f);
                float x  = d - mu;
                float sp = expf(-0.5f * x * x * pr * pr);
                sps += sp;
                if (j == myj) { spj = sp; tvj = tv[j]; ej = te[j]; }
            }
            float val = (expf(tvj - mx) / ssum) * (spj / sps);
            int   off = ((bt * KS_ + ksq) * C_ + c) * C_ + ej;
            int   slot = (((wv * 8 + jr) * 40) + lane) * 2;
            res_s[slot]     = val;
            res_s[slot + 1] = __int_as_float(off);
        }
    }

    __syncthreads();
    #pragma unroll
    for (int i = 0; i < 5; ++i) {
        int p = tid * 5 + i;
        float v   = res_s[2 * p];
        int   off = __float_as_int(res_s[2 * p + 1]);
        out[off] = v;
    }
}

extern "C" void kernel_launch(void* const* d_in, const int* in_sizes, int n_in,
                              void* d_out, int out_size, void* d_ws, size_t ws_size,
                              hipStream_t stream) {
    (void)in_sizes; (void)n_in; (void)out_size;
    const float* ctx   = (const float*)d_in[0];
    const int*   cmask = (const int*)d_in[1];
    const float* W     = (const float*)d_in[2];
    const float* mu    = (const float*)d_in[3];
    const float* pr    = (const float*)d_in[4];
    const size_t WS_NEEDED = (size_t)32 * C_ * C_ * sizeof(float);   // 33.5 MB
    if (ws_size >= WS_NEEDED) {
        float* ws = (float*)d_ws;
        gemm_attn<<<dim3(1024), dim3(256), 0, stream>>>(ctx, W, ws);
        epilogue_k<<<dim3(4096), dim3(256), 0, stream>>>(ws, cmask, mu, pr, (float*)d_out);
    } else {
        graph_learner<<<dim3(512), dim3(256), 0, stream>>>(ctx, cmask, W, mu, pr, (float*)d_out);
    }
}